// Round 1
// baseline (758.427 us; speedup 1.0000x reference)
//
#include <hip/hip_runtime.h>

// SelfAttnMatch: B=32, L=1024, D=1024, fp32 in/out.
//   scores = x @ x^T (diag zeroed); t = scores*mask; a = softmax(t)*mask;
//   alpha = a / (sum(a)+1e-13); out = alpha @ x
//
// Two-kernel MFMA (fp16 in, fp32 accum) design. d_out doubles as scratch:
// normalized alpha fp16[1024] is stored duplicated in the low/high 2048-byte
// halves of each 4096-byte output row. The PV kernel is split by d-half; each
// block reads only the alpha copy inside the exact byte range it later
// overwrites (epilogue-only writes) -> no cross-block hazards, no ws needed.

typedef _Float16 half8 __attribute__((ext_vector_type(8)));
typedef float f32x4 __attribute__((ext_vector_type(4)));

#define L_ 1024
#define D_ 1024

__device__ __forceinline__ half8 cvt8(const float* src) {
  float4 a = *(const float4*)src;
  float4 c = *(const float4*)(src + 4);
  half8 h;
  h[0] = (_Float16)a.x; h[1] = (_Float16)a.y; h[2] = (_Float16)a.z; h[3] = (_Float16)a.w;
  h[4] = (_Float16)c.x; h[5] = (_Float16)c.y; h[6] = (_Float16)c.z; h[7] = (_Float16)c.w;
  return h;
}

// ---------------------------------------------------------------------------
// Kernel B: scores + masked online-softmax -> normalized alpha (fp16, 2 copies)
// grid (8, 32) = (q-block of 128 rows, batch); 256 threads = 4 waves.
// Wave tiling: 2x2 over the 128q x 256k tile -> each wave 64q x 128k
// (4 m-tiles x 8 n-tiles of 16x16x32 f16 MFMA, acc = 128 VGPR).
// ---------------------------------------------------------------------------
__global__ __launch_bounds__(256, 2) void sam_scores_softmax(
    const float* __restrict__ x, const int* __restrict__ xmask,
    float* __restrict__ out)
{
  const int qblk = blockIdx.x;       // 0..7
  const int b    = blockIdx.y;       // 0..31
  const int tid  = threadIdx.x;
  const int wave = tid >> 6;
  const int lane = tid & 63;
  const int qh   = wave >> 1;        // q 64-half within the 128-row block
  const int kh   = wave & 1;         // key 128-half within the 256-key tile
  const int l15  = lane & 15;
  const int quad = lane >> 4;

  // stride 72 fp16 = 144 B: 16B-aligned rows, b128 bank-groups optimal (8-cyc floor)
  __shared__ _Float16 Qs[128][72];
  __shared__ _Float16 Ks[256][72];
  __shared__ float msk[256];
  __shared__ float tmax[2][128];
  __shared__ float tsum[2][128];
  __shared__ float mrun[128];
  __shared__ float lrun[128];
  __shared__ float mtile[4][128];

  if (tid < 128) { mrun[tid] = 0.0f; lrun[tid] = 0.0f; }  // diag guarantees true max >= 0

  const float* xb = x + (size_t)b * L_ * D_;

  for (int kt = 0; kt < 4; ++kt) {           // 4 key tiles of 256
    msk[tid] = (float)xmask[b * L_ + kt * 256 + tid];

    f32x4 acc[4][8];
#pragma unroll
    for (int m = 0; m < 4; ++m)
#pragma unroll
      for (int n = 0; n < 8; ++n)
#pragma unroll
        for (int r = 0; r < 4; ++r) acc[m][n][r] = 0.0f;

    for (int dc = 0; dc < 16; ++dc) {        // D in chunks of 64
      {            // stage Q: 128 rows x 64 cols (2 threads/row)
        const int row = tid >> 1, cb = (tid & 1) * 32;
        const float* src = xb + (size_t)(qblk * 128 + row) * D_ + dc * 64 + cb;
#pragma unroll
        for (int i = 0; i < 4; ++i)
          *(half8*)&Qs[row][cb + i * 8] = cvt8(src + i * 8);
      }
      {            // stage K: 256 rows x 64 cols (1 thread/row)
        const float* src = xb + (size_t)(kt * 256 + tid) * D_ + dc * 64;
#pragma unroll
        for (int i = 0; i < 8; ++i)
          *(half8*)&Ks[tid][i * 8] = cvt8(src + i * 8);
      }
      __syncthreads();
#pragma unroll
      for (int ks = 0; ks < 2; ++ks) {
        half8 af[4], bf[8];
#pragma unroll
        for (int m = 0; m < 4; ++m)
          af[m] = *(half8*)&Qs[qh * 64 + 16 * m + l15][ks * 32 + quad * 8];
#pragma unroll
        for (int n = 0; n < 8; ++n)
          bf[n] = *(half8*)&Ks[kh * 128 + 16 * n + l15][ks * 32 + quad * 8];
#pragma unroll
        for (int m = 0; m < 4; ++m)
#pragma unroll
          for (int n = 0; n < 8; ++n)
            acc[m][n] = __builtin_amdgcn_mfma_f32_16x16x32_f16(af[m], bf[n], acc[m][n], 0, 0, 0);
      }
      __syncthreads();
    }

    // ---- tile epilogue: diag zero, mask, online max/sum, store w fp16 ----
    float mkv[8];
#pragma unroll
    for (int n = 0; n < 8; ++n) mkv[n] = msk[kh * 128 + 16 * n + l15];

    float rstat[4][4];
#pragma unroll
    for (int m = 0; m < 4; ++m)
#pragma unroll
      for (int r = 0; r < 4; ++r) rstat[m][r] = 0.0f;   // t includes zeros; max >= 0 is exact

#pragma unroll
    for (int m = 0; m < 4; ++m)
#pragma unroll
      for (int r = 0; r < 4; ++r) {
        const int gq = qblk * 128 + qh * 64 + 16 * m + quad * 4 + r;
#pragma unroll
        for (int n = 0; n < 8; ++n) {
          const int gk = kt * 256 + kh * 128 + 16 * n + l15;
          float v = acc[m][n][r];
          if (gq == gk) v = 0.0f;                 // zero diagonal
          v = (mkv[n] != 0.0f) ? v : 0.0f;        // t = s * mask
          acc[m][n][r] = v;
          rstat[m][r] = fmaxf(rstat[m][r], v);
        }
      }
#pragma unroll
    for (int m = 0; m < 4; ++m)
#pragma unroll
      for (int r = 0; r < 4; ++r) {
        float v = rstat[m][r];
        v = fmaxf(v, __shfl_xor(v, 1));
        v = fmaxf(v, __shfl_xor(v, 2));
        v = fmaxf(v, __shfl_xor(v, 4));
        v = fmaxf(v, __shfl_xor(v, 8));
        rstat[m][r] = v;
      }
    if (l15 == 0) {
#pragma unroll
      for (int m = 0; m < 4; ++m)
#pragma unroll
        for (int r = 0; r < 4; ++r)
          tmax[kh][qh * 64 + 16 * m + quad * 4 + r] = rstat[m][r];
    }
    __syncthreads();

    float mnew[4][4];
#pragma unroll
    for (int m = 0; m < 4; ++m)
#pragma unroll
      for (int r = 0; r < 4; ++r) {
        const int row = qh * 64 + 16 * m + quad * 4 + r;
        mnew[m][r] = fmaxf(mrun[row], fmaxf(tmax[0][row], tmax[1][row]));
        rstat[m][r] = 0.0f;                       // reuse as row sum
      }
#pragma unroll
    for (int m = 0; m < 4; ++m)
#pragma unroll
      for (int r = 0; r < 4; ++r)
#pragma unroll
        for (int n = 0; n < 8; ++n) {
          float w = (mkv[n] != 0.0f) ? __expf(acc[m][n][r] - mnew[m][r]) : 0.0f;
          acc[m][n][r] = w;
          rstat[m][r] += w;
        }
#pragma unroll
    for (int m = 0; m < 4; ++m)
#pragma unroll
      for (int r = 0; r < 4; ++r) {
        float v = rstat[m][r];
        v += __shfl_xor(v, 1);
        v += __shfl_xor(v, 2);
        v += __shfl_xor(v, 4);
        v += __shfl_xor(v, 8);
        rstat[m][r] = v;
      }
    if (l15 == 0) {
#pragma unroll
      for (int m = 0; m < 4; ++m)
#pragma unroll
        for (int r = 0; r < 4; ++r)
          tsum[kh][qh * 64 + 16 * m + quad * 4 + r] = rstat[m][r];
    }
    __syncthreads();

    if (kh == 0 && l15 == 0) {                    // single writer per row
#pragma unroll
      for (int m = 0; m < 4; ++m)
#pragma unroll
        for (int r = 0; r < 4; ++r) {
          const int row = qh * 64 + 16 * m + quad * 4 + r;
          const float mo = mrun[row];
          const float mn = mnew[m][r];
          lrun[row] = lrun[row] * __expf(mo - mn) + tsum[0][row] + tsum[1][row];
          mrun[row] = mn;
          mtile[kt][row] = mn;
        }
    }
    // store unnormalized w (offset mnew) as fp16 into copy0 (low row half)
#pragma unroll
    for (int m = 0; m < 4; ++m)
#pragma unroll
      for (int r = 0; r < 4; ++r) {
        const int gq = qblk * 128 + qh * 64 + 16 * m + quad * 4 + r;
        _Float16* wp = (_Float16*)((char*)out + (size_t)(b * L_ + gq) * (D_ * 4));
#pragma unroll
        for (int n = 0; n < 8; ++n)
          wp[kt * 256 + kh * 128 + 16 * n + l15] = (_Float16)acc[m][n][r];
      }
    __syncthreads();
  }

  // ---- normalize: alpha = w * exp(mtile - M) / (S + 1e-13); write both copies ----
  __threadfence();   // drain + L1 invalidate so we re-read our own global writes
  __syncthreads();
  {
    const int row = tid >> 1, hf = tid & 1;       // 2 threads/row, 512 cols each
    const int gq = qblk * 128 + row;
    char* rowp = (char*)out + (size_t)(b * L_ + gq) * (D_ * 4);
    const float Mv  = mrun[row];
    const float inv = 1.0f / (lrun[row] + 1e-13f);
    const float sc0 = __expf(mtile[hf * 2    ][row] - Mv) * inv;
    const float sc1 = __expf(mtile[hf * 2 + 1][row] - Mv) * inv;
    for (int i = 0; i < 64; ++i) {
      const int col = hf * 512 + i * 8;
      const float s = (i < 32) ? sc0 : sc1;
      half8 v = *(half8*)(rowp + col * 2);
#pragma unroll
      for (int j = 0; j < 8; ++j) v[j] = (_Float16)((float)v[j] * s);
      *(half8*)(rowp + col * 2) = v;              // copy0 (read by dh=0 PV block)
      *(half8*)(rowp + 2048 + col * 2) = v;       // copy1 (read by dh=1 PV block)
    }
  }
}

// ---------------------------------------------------------------------------
// Kernel C: out = alpha @ x.  grid (16, 32): blockIdx.x = q128*2 + dh.
// 512 threads = 8 waves: wave (qh, dq) covers 64q x 128d of the block's
// 128q x 512d output (acc = 128 VGPR/lane). V transposed into LDS via
// register-pair packing (vector b128 writes). All alpha reads (from the
// block's own byte range) complete before the epilogue overwrites it.
// ---------------------------------------------------------------------------
__global__ __launch_bounds__(512, 2) void sam_pv(
    const float* __restrict__ x, float* __restrict__ out)
{
  const int q128 = blockIdx.x >> 1;  // 0..7
  const int dh   = blockIdx.x & 1;   // d half: 512 cols
  const int b    = blockIdx.y;
  const int tid  = threadIdx.x;
  const int wave = tid >> 6;
  const int lane = tid & 63;
  const int qh   = wave >> 2;        // 0/1 -> 64 q rows
  const int dq   = wave & 3;         // 0..3 -> 128 d cols
  const int l15  = lane & 15;
  const int quad = lane >> 4;

  __shared__ _Float16 Vs[512][40];   // Vs[d_local][k] = x[b][k][dh*512+d], stride 40 (16B rows)
  __shared__ _Float16 As[128][40];   // alpha tile [q][k]

  f32x4 acc[4][8];
#pragma unroll
  for (int m = 0; m < 4; ++m)
#pragma unroll
    for (int n = 0; n < 8; ++n)
#pragma unroll
      for (int r = 0; r < 4; ++r) acc[m][n][r] = 0.0f;

  const int arow  = tid >> 2, aoct = tid & 3;     // alpha staging: 4 thr/row
  const int d0    = (tid & 255) * 2;              // V staging: 2 d rows/thread
  const int khalf = tid >> 8;                     // 16-key half

  for (int kc = 0; kc < 32; ++kc) {               // 32 key chunks of 32
    // alpha tile [128 q][32 k] fp16 from this block's own copy (dh half)
    *(half8*)&As[arow][aoct * 8] =
        *(const half8*)((const char*)out +
                        (size_t)(b * L_ + q128 * 128 + arow) * (D_ * 4) +
                        dh * 2048 + kc * 64 + aoct * 16);
    // V^T tile: transpose 16k x 2d in registers, write vector rows
    {
      const float* vs = x + (size_t)(b * L_ + kc * 32 + khalf * 16) * D_ + dh * 512 + d0;
      half8 a0, a1, c0, c1;
#pragma unroll
      for (int kk = 0; kk < 8; ++kk) {
        float2 v = *(const float2*)(vs + (size_t)kk * D_);
        a0[kk] = (_Float16)v.x; c0[kk] = (_Float16)v.y;
      }
#pragma unroll
      for (int kk = 0; kk < 8; ++kk) {
        float2 v = *(const float2*)(vs + (size_t)(kk + 8) * D_);
        a1[kk] = (_Float16)v.x; c1[kk] = (_Float16)v.y;
      }
      *(half8*)&Vs[d0    ][khalf * 16    ] = a0;
      *(half8*)&Vs[d0    ][khalf * 16 + 8] = a1;
      *(half8*)&Vs[d0 + 1][khalf * 16    ] = c0;
      *(half8*)&Vs[d0 + 1][khalf * 16 + 8] = c1;
    }
    __syncthreads();
    half8 af[4], bf[8];
#pragma unroll
    for (int m = 0; m < 4; ++m)
      af[m] = *(half8*)&As[qh * 64 + 16 * m + l15][quad * 8];
#pragma unroll
    for (int n = 0; n < 8; ++n)
      bf[n] = *(half8*)&Vs[dq * 128 + 16 * n + l15][quad * 8];
#pragma unroll
    for (int m = 0; m < 4; ++m)
#pragma unroll
      for (int n = 0; n < 8; ++n)
        acc[m][n] = __builtin_amdgcn_mfma_f32_16x16x32_f16(af[m], bf[n], acc[m][n], 0, 0, 0);
    __syncthreads();
  }

  // epilogue: overwrite exactly this block's byte range (alpha fully consumed)
#pragma unroll
  for (int m = 0; m < 4; ++m)
#pragma unroll
    for (int r = 0; r < 4; ++r) {
      const int gq = q128 * 128 + qh * 64 + 16 * m + quad * 4 + r;
      float* op = out + (size_t)(b * L_ + gq) * D_ + dh * 512 + dq * 128;
#pragma unroll
      for (int n = 0; n < 8; ++n) op[16 * n + l15] = acc[m][n][r];
    }
}

extern "C" void kernel_launch(void* const* d_in, const int* in_sizes, int n_in,
                              void* d_out, int out_size, void* d_ws, size_t ws_size,
                              hipStream_t stream) {
  const float* x  = (const float*)d_in[0];
  const int*   xm = (const int*)d_in[1];
  float* out = (float*)d_out;
  (void)in_sizes; (void)n_in; (void)d_ws; (void)ws_size; (void)out_size;

  sam_scores_softmax<<<dim3(8, 32), 256, 0, stream>>>(x, xm, out);
  sam_pv<<<dim3(16, 32), 512, 0, stream>>>(x, out);
}

// Round 2
// 627.769 us; speedup vs baseline: 1.2081x; 1.2081x over previous
//
#include <hip/hip_runtime.h>

// SelfAttnMatch: B=32, L=1024, D=1024, fp32 in/out.
//   scores = x @ x^T (diag zeroed); t = scores*mask; a = softmax(t)*mask;
//   alpha = a / (sum(a)+1e-13); out = alpha @ x
//
// R2: fast path (needs ws >= 128 MB):
//   phase0: xh = fp16(x) into ws[0,64M)            (read-once convert)
//   phase1: scores+online-softmax -> normalized alpha fp16 in ws[64M,128M)
//           1024 thr / 16 waves per block  (R1 was 4 waves -> 11.7% occupancy)
//   phase2: out = alpha @ x, 512-thr blocks over (64q x 512d)
// Fallback path (small ws): R1 kernels verbatim (proven, 758 us).

typedef _Float16 half8 __attribute__((ext_vector_type(8)));
typedef float f32x4 __attribute__((ext_vector_type(4)));

#define L_ 1024
#define D_ 1024

__device__ __forceinline__ half8 cvt8(const float* src) {
  float4 a = *(const float4*)src;
  float4 c = *(const float4*)(src + 4);
  half8 h;
  h[0] = (_Float16)a.x; h[1] = (_Float16)a.y; h[2] = (_Float16)a.z; h[3] = (_Float16)a.w;
  h[4] = (_Float16)c.x; h[5] = (_Float16)c.y; h[6] = (_Float16)c.z; h[7] = (_Float16)c.w;
  return h;
}

// ===========================================================================
// FAST PATH
// ===========================================================================

// phase0: fp32 -> fp16, 32 elems/thread, grid 4096x256 covers 32*1024*1024
__global__ void sam_cvt(const float* __restrict__ x, _Float16* __restrict__ xh) {
  const size_t base = ((size_t)blockIdx.x * 256 + threadIdx.x) * 32;
  const float* src = x + base;
  _Float16* dst = xh + base;
#pragma unroll
  for (int i = 0; i < 4; ++i)
    *(half8*)(dst + i * 8) = cvt8(src + i * 8);
}

// ---------------------------------------------------------------------------
// phase1: scores + masked online-softmax -> normalized alpha fp16 (ws)
// grid (8, 32); 1024 threads = 16 waves in a 4x4 (qw,kw) grid.
// Wave tile 32q x 64k of the 128q x 256k block tile; acc = 2x4 f32x4 = 32 VGPR.
// ---------------------------------------------------------------------------
__global__ __launch_bounds__(1024, 4) void sam_scores2(
    const _Float16* __restrict__ xh, const int* __restrict__ xmask,
    _Float16* __restrict__ alpha)
{
  const int qblk = blockIdx.x;       // 0..7
  const int b    = blockIdx.y;       // 0..31
  const int tid  = threadIdx.x;
  const int wave = tid >> 6;
  const int lane = tid & 63;
  const int qw   = wave >> 2;        // 0..3 -> 32 q rows
  const int kw   = wave & 3;         // 0..3 -> 64 k cols
  const int l15  = lane & 15;
  const int quad = lane >> 4;

  __shared__ _Float16 Qs[128][72];   // stride 72 fp16 = 144 B (16B-aligned rows, 2-way banks)
  __shared__ _Float16 Ks[256][72];
  __shared__ float msk[256];
  __shared__ float tmax[4][128];
  __shared__ float tsum[4][128];
  __shared__ float mrun[128];
  __shared__ float lrun[128];
  __shared__ float mtile[4][128];

  if (tid < 128) { mrun[tid] = 0.0f; lrun[tid] = 0.0f; }  // diag/mask-zeros => true max >= 0

  const _Float16* xb = xh + (size_t)b * L_ * D_;
  const int srow = tid >> 3;             // staging: row, 8 thr/row
  const int scol = (tid & 7) * 8;        // 16-B chunk

  for (int kt = 0; kt < 4; ++kt) {       // 4 key tiles of 256
    if (tid < 256) msk[tid] = (float)xmask[b * L_ + kt * 256 + tid];

    f32x4 acc[2][4];
#pragma unroll
    for (int m = 0; m < 2; ++m)
#pragma unroll
      for (int n = 0; n < 4; ++n)
#pragma unroll
        for (int r = 0; r < 4; ++r) acc[m][n][r] = 0.0f;

    for (int dc = 0; dc < 16; ++dc) {    // D in chunks of 64
      // stage Q: 128 x 64 fp16 (one half8 per thread)
      *(half8*)&Qs[srow][scol] =
          *(const half8*)(xb + (size_t)(qblk * 128 + srow) * D_ + dc * 64 + scol);
      // stage K: 256 x 64 fp16 (two half8 per thread)
#pragma unroll
      for (int i = 0; i < 2; ++i)
        *(half8*)&Ks[srow + 128 * i][scol] =
            *(const half8*)(xb + (size_t)(kt * 256 + srow + 128 * i) * D_ + dc * 64 + scol);
      __syncthreads();
#pragma unroll
      for (int ks = 0; ks < 2; ++ks) {
        half8 af[2], bf[4];
#pragma unroll
        for (int m = 0; m < 2; ++m)
          af[m] = *(half8*)&Qs[qw * 32 + 16 * m + l15][ks * 32 + quad * 8];
#pragma unroll
        for (int n = 0; n < 4; ++n)
          bf[n] = *(half8*)&Ks[kw * 64 + 16 * n + l15][ks * 32 + quad * 8];
#pragma unroll
        for (int m = 0; m < 2; ++m)
#pragma unroll
          for (int n = 0; n < 4; ++n)
            acc[m][n] = __builtin_amdgcn_mfma_f32_16x16x32_f16(af[m], bf[n], acc[m][n], 0, 0, 0);
      }
      __syncthreads();
    }

    // ---- tile epilogue: diag zero, mask, online max/sum, store w fp16 ----
    float mkv[4];
#pragma unroll
    for (int n = 0; n < 4; ++n) mkv[n] = msk[kw * 64 + 16 * n + l15];

    float rst[2][4];
#pragma unroll
    for (int m = 0; m < 2; ++m)
#pragma unroll
      for (int r = 0; r < 4; ++r) rst[m][r] = 0.0f;

#pragma unroll
    for (int m = 0; m < 2; ++m)
#pragma unroll
      for (int r = 0; r < 4; ++r) {
        const int gq = qblk * 128 + qw * 32 + 16 * m + quad * 4 + r;
#pragma unroll
        for (int n = 0; n < 4; ++n) {
          const int gk = kt * 256 + kw * 64 + 16 * n + l15;
          float v = acc[m][n][r];
          if (gq == gk) v = 0.0f;                 // zero diagonal
          v = (mkv[n] != 0.0f) ? v : 0.0f;        // t = s * mask
          acc[m][n][r] = v;
          rst[m][r] = fmaxf(rst[m][r], v);
        }
      }
#pragma unroll
    for (int m = 0; m < 2; ++m)
#pragma unroll
      for (int r = 0; r < 4; ++r) {
        float v = rst[m][r];
        v = fmaxf(v, __shfl_xor(v, 1));
        v = fmaxf(v, __shfl_xor(v, 2));
        v = fmaxf(v, __shfl_xor(v, 4));
        v = fmaxf(v, __shfl_xor(v, 8));
        rst[m][r] = v;
      }
    if (l15 == 0) {
#pragma unroll
      for (int m = 0; m < 2; ++m)
#pragma unroll
        for (int r = 0; r < 4; ++r)
          tmax[kw][qw * 32 + 16 * m + quad * 4 + r] = rst[m][r];
    }
    __syncthreads();                              // barrier A

    float mnew[2][4];
#pragma unroll
    for (int m = 0; m < 2; ++m)
#pragma unroll
      for (int r = 0; r < 4; ++r) {
        const int row = qw * 32 + 16 * m + quad * 4 + r;
        mnew[m][r] = fmaxf(fmaxf(mrun[row], fmaxf(tmax[0][row], tmax[1][row])),
                           fmaxf(tmax[2][row], tmax[3][row]));
        rst[m][r] = 0.0f;                         // reuse as row sum
      }
#pragma unroll
    for (int m = 0; m < 2; ++m)
#pragma unroll
      for (int r = 0; r < 4; ++r)
#pragma unroll
        for (int n = 0; n < 4; ++n) {
          float w = (mkv[n] != 0.0f) ? __expf(acc[m][n][r] - mnew[m][r]) : 0.0f;
          acc[m][n][r] = w;
          rst[m][r] += w;
        }
#pragma unroll
    for (int m = 0; m < 2; ++m)
#pragma unroll
      for (int r = 0; r < 4; ++r) {
        float v = rst[m][r];
        v += __shfl_xor(v, 1);
        v += __shfl_xor(v, 2);
        v += __shfl_xor(v, 4);
        v += __shfl_xor(v, 8);
        rst[m][r] = v;
      }
    if (l15 == 0) {
#pragma unroll
      for (int m = 0; m < 2; ++m)
#pragma unroll
        for (int r = 0; r < 4; ++r)
          tsum[kw][qw * 32 + 16 * m + quad * 4 + r] = rst[m][r];
    }
    __syncthreads();                              // barrier B

    if (kw == 0 && l15 == 0) {                    // single writer per row
#pragma unroll
      for (int m = 0; m < 2; ++m)
#pragma unroll
        for (int r = 0; r < 4; ++r) {
          const int row = qw * 32 + 16 * m + quad * 4 + r;
          const float mo = mrun[row];
          const float mn = mnew[m][r];
          lrun[row] = lrun[row] * __expf(mo - mn) +
                      tsum[0][row] + tsum[1][row] + tsum[2][row] + tsum[3][row];
          mrun[row] = mn;
          mtile[kt][row] = mn;
        }
    }
    // store unnormalized w (offset mnew) as fp16 into alpha (ws)
#pragma unroll
    for (int m = 0; m < 2; ++m)
#pragma unroll
      for (int r = 0; r < 4; ++r) {
        const int gq = qblk * 128 + qw * 32 + 16 * m + quad * 4 + r;
        _Float16* wp = alpha + ((size_t)(b * L_ + gq)) * L_;
#pragma unroll
        for (int n = 0; n < 4; ++n)
          wp[kt * 256 + kw * 64 + 16 * n + l15] = (_Float16)acc[m][n][r];
      }
    __syncthreads();                              // barrier C
  }

  // ---- normalize: alpha = w * exp(mtile - M) / (S + 1e-13) ----
  __threadfence();   // drain our global w-stores before re-reading them
  __syncthreads();
  {
    const int row = tid >> 3;                     // 8 threads/row
    const int seg = tid & 7;                      // 128 cols each (within one kt)
    _Float16* rp = alpha + ((size_t)(b * L_ + qblk * 128 + row)) * L_ + seg * 128;
    const float Mv  = mrun[row];
    const float inv = 1.0f / (lrun[row] + 1e-13f);
    const float sc  = __expf(mtile[seg >> 1][row] - Mv) * inv;
    for (int i = 0; i < 16; ++i) {
      half8 v = *(half8*)(rp + i * 8);
#pragma unroll
      for (int j = 0; j < 8; ++j) v[j] = (_Float16)((float)v[j] * sc);
      *(half8*)(rp + i * 8) = v;
    }
  }
}

// ---------------------------------------------------------------------------
// phase2: out = alpha @ x.  grid (32, 32): blockIdx.x = qb*2 + dh.
// 512 threads = 8 waves (qw 0..1, dw 0..3); wave tile 32q x 128d; acc 64 VGPR.
// V transposed into LDS via fp16-pair register packing.
// ---------------------------------------------------------------------------
__global__ __launch_bounds__(512, 3) void sam_pv2(
    const _Float16* __restrict__ xh, const _Float16* __restrict__ alpha,
    float* __restrict__ out)
{
  const int qb   = blockIdx.x >> 1;  // 0..15 -> 64 q rows
  const int dh   = blockIdx.x & 1;   // d half: 512 cols
  const int b    = blockIdx.y;
  const int tid  = threadIdx.x;
  const int wave = tid >> 6;
  const int lane = tid & 63;
  const int qw   = wave >> 2;        // 0..1 -> 32 q rows
  const int dw   = wave & 3;         // 0..3 -> 128 d cols
  const int l15  = lane & 15;
  const int quad = lane >> 4;

  __shared__ _Float16 Vs[512][40];   // Vs[d_local][k], stride 40 fp16 = 80 B
  __shared__ _Float16 As[64][40];    // alpha tile [q][k]

  f32x4 acc[2][8];
#pragma unroll
  for (int m = 0; m < 2; ++m)
#pragma unroll
    for (int n = 0; n < 8; ++n)
#pragma unroll
      for (int r = 0; r < 4; ++r) acc[m][n][r] = 0.0f;

  const int d0 = (tid & 255) * 2;    // V staging: 2 adjacent d rows/thread
  const int kh = tid >> 8;           // 16-key half

  for (int kc = 0; kc < 32; ++kc) {  // 32 key chunks of 32
    if (tid < 256) {                 // alpha tile 64q x 32k
      const int ar = tid >> 2, ac = tid & 3;
      *(half8*)&As[ar][ac * 8] =
          *(const half8*)(alpha + ((size_t)(b * L_ + qb * 64 + ar)) * L_ + kc * 32 + ac * 8);
    }
    {                                // V^T tile: 16k x 2d register transpose
      const _Float16* vp = xh + ((size_t)(b * L_ + kc * 32 + kh * 16)) * D_ + dh * 512 + d0;
      half8 a0, a1, c0, c1;
#pragma unroll
      for (int kk = 0; kk < 8; ++kk) {
        union { unsigned int u; _Float16 h[2]; } cv;
        cv.u = *(const unsigned int*)(vp + (size_t)kk * D_);
        a0[kk] = cv.h[0]; c0[kk] = cv.h[1];
      }
#pragma unroll
      for (int kk = 0; kk < 8; ++kk) {
        union { unsigned int u; _Float16 h[2]; } cv;
        cv.u = *(const unsigned int*)(vp + (size_t)(kk + 8) * D_);
        a1[kk] = cv.h[0]; c1[kk] = cv.h[1];
      }
      *(half8*)&Vs[d0    ][kh * 16    ] = a0;
      *(half8*)&Vs[d0    ][kh * 16 + 8] = a1;
      *(half8*)&Vs[d0 + 1][kh * 16    ] = c0;
      *(half8*)&Vs[d0 + 1][kh * 16 + 8] = c1;
    }
    __syncthreads();
    half8 af[2], bf[8];
#pragma unroll
    for (int m = 0; m < 2; ++m)
      af[m] = *(half8*)&As[qw * 32 + 16 * m + l15][quad * 8];
#pragma unroll
    for (int n = 0; n < 8; ++n)
      bf[n] = *(half8*)&Vs[dw * 128 + 16 * n + l15][quad * 8];
#pragma unroll
    for (int m = 0; m < 2; ++m)
#pragma unroll
      for (int n = 0; n < 8; ++n)
        acc[m][n] = __builtin_amdgcn_mfma_f32_16x16x32_f16(af[m], bf[n], acc[m][n], 0, 0, 0);
    __syncthreads();
  }

#pragma unroll
  for (int m = 0; m < 2; ++m)
#pragma unroll
    for (int r = 0; r < 4; ++r) {
      const int gq = qb * 64 + qw * 32 + 16 * m + quad * 4 + r;
      float* op = out + (size_t)(b * L_ + gq) * D_ + dh * 512 + dw * 128;
#pragma unroll
      for (int n = 0; n < 8; ++n) op[16 * n + l15] = acc[m][n][r];
    }
}

// ===========================================================================
// FALLBACK PATH (R1, proven): used when ws_size < 128 MB
// ===========================================================================

__global__ __launch_bounds__(256, 2) void sam_scores_softmax(
    const float* __restrict__ x, const int* __restrict__ xmask,
    float* __restrict__ out)
{
  const int qblk = blockIdx.x;
  const int b    = blockIdx.y;
  const int tid  = threadIdx.x;
  const int wave = tid >> 6;
  const int lane = tid & 63;
  const int qh   = wave >> 1;
  const int kh   = wave & 1;
  const int l15  = lane & 15;
  const int quad = lane >> 4;

  __shared__ _Float16 Qs[128][72];
  __shared__ _Float16 Ks[256][72];
  __shared__ float msk[256];
  __shared__ float tmax[2][128];
  __shared__ float tsum[2][128];
  __shared__ float mrun[128];
  __shared__ float lrun[128];
  __shared__ float mtile[4][128];

  if (tid < 128) { mrun[tid] = 0.0f; lrun[tid] = 0.0f; }

  const float* xb = x + (size_t)b * L_ * D_;

  for (int kt = 0; kt < 4; ++kt) {
    msk[tid] = (float)xmask[b * L_ + kt * 256 + tid];

    f32x4 acc[4][8];
#pragma unroll
    for (int m = 0; m < 4; ++m)
#pragma unroll
      for (int n = 0; n < 8; ++n)
#pragma unroll
        for (int r = 0; r < 4; ++r) acc[m][n][r] = 0.0f;

    for (int dc = 0; dc < 16; ++dc) {
      {
        const int row = tid >> 1, cb = (tid & 1) * 32;
        const float* src = xb + (size_t)(qblk * 128 + row) * D_ + dc * 64 + cb;
#pragma unroll
        for (int i = 0; i < 4; ++i)
          *(half8*)&Qs[row][cb + i * 8] = cvt8(src + i * 8);
      }
      {
        const float* src = xb + (size_t)(kt * 256 + tid) * D_ + dc * 64;
#pragma unroll
        for (int i = 0; i < 8; ++i)
          *(half8*)&Ks[tid][i * 8] = cvt8(src + i * 8);
      }
      __syncthreads();
#pragma unroll
      for (int ks = 0; ks < 2; ++ks) {
        half8 af[4], bf[8];
#pragma unroll
        for (int m = 0; m < 4; ++m)
          af[m] = *(half8*)&Qs[qh * 64 + 16 * m + l15][ks * 32 + quad * 8];
#pragma unroll
        for (int n = 0; n < 8; ++n)
          bf[n] = *(half8*)&Ks[kh * 128 + 16 * n + l15][ks * 32 + quad * 8];
#pragma unroll
        for (int m = 0; m < 4; ++m)
#pragma unroll
          for (int n = 0; n < 8; ++n)
            acc[m][n] = __builtin_amdgcn_mfma_f32_16x16x32_f16(af[m], bf[n], acc[m][n], 0, 0, 0);
      }
      __syncthreads();
    }

    float mkv[8];
#pragma unroll
    for (int n = 0; n < 8; ++n) mkv[n] = msk[kh * 128 + 16 * n + l15];

    float rstat[4][4];
#pragma unroll
    for (int m = 0; m < 4; ++m)
#pragma unroll
      for (int r = 0; r < 4; ++r) rstat[m][r] = 0.0f;

#pragma unroll
    for (int m = 0; m < 4; ++m)
#pragma unroll
      for (int r = 0; r < 4; ++r) {
        const int gq = qblk * 128 + qh * 64 + 16 * m + quad * 4 + r;
#pragma unroll
        for (int n = 0; n < 8; ++n) {
          const int gk = kt * 256 + kh * 128 + 16 * n + l15;
          float v = acc[m][n][r];
          if (gq == gk) v = 0.0f;
          v = (mkv[n] != 0.0f) ? v : 0.0f;
          acc[m][n][r] = v;
          rstat[m][r] = fmaxf(rstat[m][r], v);
        }
      }
#pragma unroll
    for (int m = 0; m < 4; ++m)
#pragma unroll
      for (int r = 0; r < 4; ++r) {
        float v = rstat[m][r];
        v = fmaxf(v, __shfl_xor(v, 1));
        v = fmaxf(v, __shfl_xor(v, 2));
        v = fmaxf(v, __shfl_xor(v, 4));
        v = fmaxf(v, __shfl_xor(v, 8));
        rstat[m][r] = v;
      }
    if (l15 == 0) {
#pragma unroll
      for (int m = 0; m < 4; ++m)
#pragma unroll
        for (int r = 0; r < 4; ++r)
          tmax[kh][qh * 64 + 16 * m + quad * 4 + r] = rstat[m][r];
    }
    __syncthreads();

    float mnew[4][4];
#pragma unroll
    for (int m = 0; m < 4; ++m)
#pragma unroll
      for (int r = 0; r < 4; ++r) {
        const int row = qh * 64 + 16 * m + quad * 4 + r;
        mnew[m][r] = fmaxf(mrun[row], fmaxf(tmax[0][row], tmax[1][row]));
        rstat[m][r] = 0.0f;
      }
#pragma unroll
    for (int m = 0; m < 4; ++m)
#pragma unroll
      for (int r = 0; r < 4; ++r)
#pragma unroll
        for (int n = 0; n < 8; ++n) {
          float w = (mkv[n] != 0.0f) ? __expf(acc[m][n][r] - mnew[m][r]) : 0.0f;
          acc[m][n][r] = w;
          rstat[m][r] += w;
        }
#pragma unroll
    for (int m = 0; m < 4; ++m)
#pragma unroll
      for (int r = 0; r < 4; ++r) {
        float v = rstat[m][r];
        v += __shfl_xor(v, 1);
        v += __shfl_xor(v, 2);
        v += __shfl_xor(v, 4);
        v += __shfl_xor(v, 8);
        rstat[m][r] = v;
      }
    if (l15 == 0) {
#pragma unroll
      for (int m = 0; m < 4; ++m)
#pragma unroll
        for (int r = 0; r < 4; ++r)
          tsum[kh][qh * 64 + 16 * m + quad * 4 + r] = rstat[m][r];
    }
    __syncthreads();

    if (kh == 0 && l15 == 0) {
#pragma unroll
      for (int m = 0; m < 4; ++m)
#pragma unroll
        for (int r = 0; r < 4; ++r) {
          const int row = qh * 64 + 16 * m + quad * 4 + r;
          const float mo = mrun[row];
          const float mn = mnew[m][r];
          lrun[row] = lrun[row] * __expf(mo - mn) + tsum[0][row] + tsum[1][row];
          mrun[row] = mn;
          mtile[kt][row] = mn;
        }
    }
#pragma unroll
    for (int m = 0; m < 4; ++m)
#pragma unroll
      for (int r = 0; r < 4; ++r) {
        const int gq = qblk * 128 + qh * 64 + 16 * m + quad * 4 + r;
        _Float16* wp = (_Float16*)((char*)out + (size_t)(b * L_ + gq) * (D_ * 4));
#pragma unroll
        for (int n = 0; n < 8; ++n)
          wp[kt * 256 + kh * 128 + 16 * n + l15] = (_Float16)acc[m][n][r];
      }
    __syncthreads();
  }

  __threadfence();
  __syncthreads();
  {
    const int row = tid >> 1, hf = tid & 1;
    const int gq = qblk * 128 + row;
    char* rowp = (char*)out + (size_t)(b * L_ + gq) * (D_ * 4);
    const float Mv  = mrun[row];
    const float inv = 1.0f / (lrun[row] + 1e-13f);
    const float sc0 = __expf(mtile[hf * 2    ][row] - Mv) * inv;
    const float sc1 = __expf(mtile[hf * 2 + 1][row] - Mv) * inv;
    for (int i = 0; i < 64; ++i) {
      const int col = hf * 512 + i * 8;
      const float s = (i < 32) ? sc0 : sc1;
      half8 v = *(half8*)(rowp + col * 2);
#pragma unroll
      for (int j = 0; j < 8; ++j) v[j] = (_Float16)((float)v[j] * s);
      *(half8*)(rowp + col * 2) = v;
      *(half8*)(rowp + 2048 + col * 2) = v;
    }
  }
}

__global__ __launch_bounds__(512, 2) void sam_pv(
    const float* __restrict__ x, float* __restrict__ out)
{
  const int q128 = blockIdx.x >> 1;
  const int dh   = blockIdx.x & 1;
  const int b    = blockIdx.y;
  const int tid  = threadIdx.x;
  const int wave = tid >> 6;
  const int lane = tid & 63;
  const int qh   = wave >> 2;
  const int dq   = wave & 3;
  const int l15  = lane & 15;
  const int quad = lane >> 4;

  __shared__ _Float16 Vs[512][40];
  __shared__ _Float16 As[128][40];

  f32x4 acc[4][8];
#pragma unroll
  for (int m = 0; m < 4; ++m)
#pragma unroll
    for (int n = 0; n < 8; ++n)
#pragma unroll
      for (int r = 0; r < 4; ++r) acc[m][n][r] = 0.0f;

  const int arow  = tid >> 2, aoct = tid & 3;
  const int d0    = (tid & 255) * 2;
  const int khalf = tid >> 8;

  for (int kc = 0; kc < 32; ++kc) {
    *(half8*)&As[arow][aoct * 8] =
        *(const half8*)((const char*)out +
                        (size_t)(b * L_ + q128 * 128 + arow) * (D_ * 4) +
                        dh * 2048 + kc * 64 + aoct * 16);
    {
      const float* vs = x + (size_t)(b * L_ + kc * 32 + khalf * 16) * D_ + dh * 512 + d0;
      half8 a0, a1, c0, c1;
#pragma unroll
      for (int kk = 0; kk < 8; ++kk) {
        float2 v = *(const float2*)(vs + (size_t)kk * D_);
        a0[kk] = (_Float16)v.x; c0[kk] = (_Float16)v.y;
      }
#pragma unroll
      for (int kk = 0; kk < 8; ++kk) {
        float2 v = *(const float2*)(vs + (size_t)(kk + 8) * D_);
        a1[kk] = (_Float16)v.x; c1[kk] = (_Float16)v.y;
      }
      *(half8*)&Vs[d0    ][khalf * 16    ] = a0;
      *(half8*)&Vs[d0    ][khalf * 16 + 8] = a1;
      *(half8*)&Vs[d0 + 1][khalf * 16    ] = c0;
      *(half8*)&Vs[d0 + 1][khalf * 16 + 8] = c1;
    }
    __syncthreads();
    half8 af[4], bf[8];
#pragma unroll
    for (int m = 0; m < 4; ++m)
      af[m] = *(half8*)&As[qh * 64 + 16 * m + l15][quad * 8];
#pragma unroll
    for (int n = 0; n < 8; ++n)
      bf[n] = *(half8*)&Vs[dq * 128 + 16 * n + l15][quad * 8];
#pragma unroll
    for (int m = 0; m < 4; ++m)
#pragma unroll
      for (int n = 0; n < 8; ++n)
        acc[m][n] = __builtin_amdgcn_mfma_f32_16x16x32_f16(af[m], bf[n], acc[m][n], 0, 0, 0);
    __syncthreads();
  }

#pragma unroll
  for (int m = 0; m < 4; ++m)
#pragma unroll
    for (int r = 0; r < 4; ++r) {
      const int gq = q128 * 128 + qh * 64 + 16 * m + quad * 4 + r;
      float* op = out + (size_t)(b * L_ + gq) * D_ + dh * 512 + dq * 128;
#pragma unroll
      for (int n = 0; n < 8; ++n) op[16 * n + l15] = acc[m][n][r];
    }
}

extern "C" void kernel_launch(void* const* d_in, const int* in_sizes, int n_in,
                              void* d_out, int out_size, void* d_ws, size_t ws_size,
                              hipStream_t stream) {
  const float* x  = (const float*)d_in[0];
  const int*   xm = (const int*)d_in[1];
  float* out = (float*)d_out;
  (void)in_sizes; (void)n_in; (void)out_size;

  if (ws_size >= (size_t)128 * 1024 * 1024) {
    _Float16* xhp = (_Float16*)d_ws;
    _Float16* alp = (_Float16*)((char*)d_ws + (size_t)64 * 1024 * 1024);
    sam_cvt<<<4096, 256, 0, stream>>>(x, xhp);
    sam_scores2<<<dim3(8, 32), 1024, 0, stream>>>(xhp, xm, alp);
    sam_pv2<<<dim3(32, 32), 512, 0, stream>>>(xhp, alp, out);
  } else {
    sam_scores_softmax<<<dim3(8, 32), 256, 0, stream>>>(x, xm, out);
    sam_pv<<<dim3(16, 32), 512, 0, stream>>>(x, out);
  }
}